// Round 2
// baseline (4314.922 us; speedup 1.0000x reference)
//
#include <hip/hip_runtime.h>
#include <math.h>

#define FD 64
#define NRBF 20
#define CUT 5.0f
#define EPSV 1e-8f
#define PI_F 3.14159265358979f

__device__ __forceinline__ float wredsum(float v){
#pragma unroll
  for (int m = 32; m >= 1; m >>= 1) v += __shfl_xor(v, m, 64);
  return v;
}
__device__ __forceinline__ float wredmax(float v){
#pragma unroll
  for (int m = 32; m >= 1; m >>= 1) v = fmaxf(v, __shfl_xor(v, m, 64));
  return v;
}
__device__ __forceinline__ float silu_f(float x){ return x * (1.0f / (1.0f + __expf(-x))); }

// ---- K0: per-pair precompute: dir(3), fcut(1), phi*fcut(20) -> 24 floats ----
__global__ __launch_bounds__(256) void k_pairprep(const float* __restrict__ Rij,
                                                  float* __restrict__ pair, int P)
{
  int p = blockIdx.x * blockDim.x + threadIdx.x;
  if (p >= P) return;
  float rx = Rij[3*p+0], ry = Rij[3*p+1], rz = Rij[3*p+2];
  float d = sqrtf(rx*rx + ry*ry + rz*rz);
  float inv = 1.0f / d;
  float fc = (d < CUT) ? 0.5f * (__cosf(PI_F * d / CUT) + 1.0f) : 0.0f;
  float* pr = pair + (size_t)p * 24;
  pr[0] = rx*inv; pr[1] = ry*inv; pr[2] = rz*inv; pr[3] = fc;
  const float width = CUT / (float)(NRBF - 1);
#pragma unroll
  for (int r = 0; r < NRBF; ++r){
    float t = (d - width * (float)r) / width;
    pr[4+r] = __expf(-0.5f * t * t) * fc;
  }
}

// ---- transpose rec_W2 -> rW2T[l][c][k][f], rb2 -> rb2T[l][c][f] ----
__global__ __launch_bounds__(256) void k_transpose_w(const float* __restrict__ rW2,
                                                     const float* __restrict__ rb2,
                                                     float* __restrict__ rW2T,
                                                     float* __restrict__ rb2T)
{
  int t = blockIdx.x * blockDim.x + threadIdx.x;
  if (t >= 2*64*32*64) return;
  int f = t & 63;
  int k = (t >> 6) & 31;
  int c = (t >> 11) & 63;
  int l = t >> 17;
  rW2T[t] = rW2[((size_t)l*32 + k)*4096 + f*64 + c];
  if (k == 0) rb2T[((size_t)l*64 + c)*64 + f] = rb2[(size_t)l*4096 + f*64 + c];
}

// ---- K_init: q = embed[Z] ----
__global__ __launch_bounds__(256) void k_init_q(const int* __restrict__ Z,
                                                const float* __restrict__ embed,
                                                float* __restrict__ q, int Ntot)
{
  int t = blockIdx.x * blockDim.x + threadIdx.x;
  if (t >= Ntot * FD) return;
  int n = t >> 6, f = t & 63;
  q[t] = embed[Z[n]*FD + f];
}

// ---- K1: per-atom: X = silu(q@cW1+cb1)@cW2+cb2 ; CV = compress(mu) ----
__global__ __launch_bounds__(256) void k_atom_pre(
    const float* __restrict__ q, const float* __restrict__ mu,
    const float* __restrict__ cW1, const float* __restrict__ cb1,
    const float* __restrict__ cW2, const float* __restrict__ cb2,
    const float* __restrict__ pW1, const float* __restrict__ pb1,
    const float* __restrict__ pW2, const float* __restrict__ pb2,
    float* __restrict__ X, float* __restrict__ CV, int Ntot)
{
  __shared__ float qs[4][64];
  __shared__ float h1[4][64];
  __shared__ float sbuf[4][128];
  __shared__ float hc[4][32];
  int w = threadIdx.x >> 6;
  int f = threadIdx.x & 63;
  int n = blockIdx.x * 4 + w;
  bool ok = (n < Ntot);
  if (!ok) n = Ntot - 1;

  float qv = q[(size_t)n*64 + f];
  qs[w][f] = qv;

  const float* mun = mu + (size_t)n * 384;
  float m0a = mun[0*128 + f],      m1a = mun[1*128 + f],      m2a = mun[2*128 + f];
  float m0b = mun[0*128 + 64 + f], m1b = mun[1*128 + 64 + f], m2b = mun[2*128 + 64 + f];
  sbuf[w][f]      = sqrtf(m0a*m0a + m1a*m1a + m2a*m2a + EPSV);
  sbuf[w][64 + f] = sqrtf(m0b*m0b + m1b*m1b + m2b*m2b + EPSV);

  float acc = cb1[f];
#pragma unroll
  for (int k = 0; k < 64; ++k) acc = fmaf(qs[w][k], cW1[k*64 + f], acc);
  h1[w][f] = silu_f(acc);

  float x0 = cb2[f], x1 = cb2[64+f], x2 = cb2[128+f];
#pragma unroll
  for (int k = 0; k < 64; ++k){
    float h = h1[w][k];
    x0 = fmaf(h, cW2[k*192 + f],       x0);
    x1 = fmaf(h, cW2[k*192 + 64 + f],  x1);
    x2 = fmaf(h, cW2[k*192 + 128 + f], x2);
  }
  if (ok){
    float* Xn = X + (size_t)n*192;
    Xn[f] = x0; Xn[64+f] = x1; Xn[128+f] = x2;
  }

  int ki = f & 31;
  float ah = pb1[ki];
#pragma unroll
  for (int c = 0; c < 128; ++c) ah = fmaf(sbuf[w][c], pW1[c*32 + ki], ah);
  if (f < 32) hc[w][f] = fmaxf(ah, 0.0f);

  float logit = pb2[f];
#pragma unroll
  for (int k = 0; k < 32; ++k) logit = fmaf(hc[w][k], pW2[k*64 + f], logit);
  float mx = wredmax(logit);
  float e  = __expf(logit - mx);
  float se = wredsum(e);
  float wt = e / se;
  float v0 = wredsum(m0a + m0b);
  float v1 = wredsum(m1a + m1b);
  float v2 = wredsum(m2a + m2b);
  if (ok){
    float* cvn = CV + (size_t)n*192;
    cvn[f] = v0 * wt; cvn[64+f] = v1 * wt; cvn[128+f] = v2 * wt;
  }
}

// ---- K2: per-pair: filters on the fly, gather X[j], CV[j], atomic scatter to i ----
__global__ __launch_bounds__(256) void k_edge(
    const float* __restrict__ pair, const int* __restrict__ idx_i, const int* __restrict__ idx_j,
    const float* __restrict__ fW, const float* __restrict__ fb,
    const float* __restrict__ X, const float* __restrict__ CV,
    float* __restrict__ dq, float* __restrict__ dmu, int l, int P)
{
  int w = threadIdx.x >> 6;
  int f = threadIdx.x & 63;
  int p = blockIdx.x * 4 + w;
  if (p >= P) return;
  const float* pr = pair + (size_t)p * 24;
  float d0 = pr[0], d1 = pr[1], d2 = pr[2], fc = pr[3];
  int i = idx_i[p], j = idx_j[p];
  const int col = l * 192;
  float w0 = fb[col + f] * fc, w1 = fb[col + 64 + f] * fc, w2 = fb[col + 128 + f] * fc;
#pragma unroll
  for (int r = 0; r < NRBF; ++r){
    float ph = pr[4 + r];
    const float* fr = fW + r*384 + col;
    w0 = fmaf(ph, fr[f],       w0);
    w1 = fmaf(ph, fr[64 + f],  w1);
    w2 = fmaf(ph, fr[128 + f], w2);
  }
  const float* Xj = X + (size_t)j * 192;
  float dqv = Xj[f]       * w0;
  float dmR = Xj[64 + f]  * w1;
  float dmm = Xj[128 + f] * w2;
  const float* cvj = CV + (size_t)j * 192;
  atomicAdd(&dq[(size_t)i*64 + f], dqv);
  atomicAdd(&dmu[(size_t)i*192 + f],       fmaf(dmR, d0, dmm * cvj[f]));
  atomicAdd(&dmu[(size_t)i*192 + 64 + f],  fmaf(dmR, d1, dmm * cvj[64 + f]));
  atomicAdd(&dmu[(size_t)i*192 + 128 + f], fmaf(dmR, d2, dmm * cvj[128 + f]));
}

// ---- K3 v2: per-atom post. 4 waves/block, 2 atoms/wave (8 atoms/block).
// c-outer/k-inner contraction with transposed rW2T[c][k][f]; h in registers via shfl.
__global__ __launch_bounds__(256) void k_atom_post(
    float* __restrict__ q, float* __restrict__ mu,
    const float* __restrict__ dq, const float* __restrict__ dmuA, const float* __restrict__ CV,
    const float* __restrict__ rW1, const float* __restrict__ rb1,
    const float* __restrict__ rW2T, const float* __restrict__ rb2T,
    const float* __restrict__ mW1, const float* __restrict__ mb1,
    const float* __restrict__ mW2, const float* __restrict__ mb2,
    const float* __restrict__ Wm, int Ntot)
{
  __shared__ float mus[8][3][64];
  __shared__ float svs[8][64];
  __shared__ float avs[4][128];
  __shared__ float h2s[4][64];
  int w = threadIdx.x >> 6;
  int f = threadIdx.x & 63;
  int base = blockIdx.x * 8 + w * 2;

  float qv[2], mf[2][3];
#pragma unroll
  for (int s = 0; s < 2; ++s){
    int n = base + s; if (n >= Ntot) n = Ntot - 1;
    qv[s] = q[(size_t)n*64 + f] + dq[(size_t)n*64 + f];
    const float* dmn = dmuA + (size_t)n*192;
    const float* cvn = CV   + (size_t)n*192;
    float m0 = dmn[f]       + cvn[f];
    float m1 = dmn[64 + f]  + cvn[64 + f];
    float m2 = dmn[128 + f] + cvn[128 + f];
    mf[s][0] = m0; mf[s][1] = m1; mf[s][2] = m2;
    int a = w*2 + s;
    mus[a][0][f] = m0; mus[a][1][f] = m1; mus[a][2][f] = m2;
    svs[a][f] = sqrtf(m0*m0 + m1*m1 + m2*m2 + EPSV);
  }

  // rec MLP layer 1: h[a][k] = relu(sv[a] @ rW1 + rb1); broadcast to registers
  int ki = f & 31;
  float hreg[2][32];
#pragma unroll
  for (int s = 0; s < 2; ++s){
    int a = w*2 + s;
    float ah = rb1[ki];
#pragma unroll
    for (int c = 0; c < 64; ++c) ah = fmaf(svs[a][c], rW1[c*32 + ki], ah);
    ah = fmaxf(ah, 0.0f);
#pragma unroll
    for (int k = 0; k < 32; ++k) hreg[s][k] = __shfl(ah, k, 64);
  }

  // fused sw/tv: tv[s][d] = sum_c mus[a][d][c] * sw[f,c] * G[c,f]
  const int a0 = w*2, a1 = w*2 + 1;
  float tv00=0,tv01=0,tv02=0, tv10=0,tv11=0,tv12=0;
  for (int c = 0; c < 64; ++c){
    float u00 = mus[a0][0][c], u01 = mus[a0][1][c], u02 = mus[a0][2][c];
    float u10 = mus[a1][0][c], u11 = mus[a1][1][c], u12 = mus[a1][2][c];
    float g0 = u00*mf[0][0] + u01*mf[0][1] + u02*mf[0][2];
    float g1 = u10*mf[1][0] + u11*mf[1][1] + u12*mf[1][2];
    float acc0 = rb2T[c*64 + f];
    float acc1 = acc0;
    const float* wc = rW2T + (size_t)c*2048 + f;
#pragma unroll
    for (int k = 0; k < 32; ++k){
      float wv = wc[k*64];
      acc0 = fmaf(hreg[0][k], wv, acc0);
      acc1 = fmaf(hreg[1][k], wv, acc1);
    }
    float mm0 = acc0 * g0, mm1 = acc1 * g1;
    tv00 = fmaf(u00, mm0, tv00); tv01 = fmaf(u01, mm0, tv01); tv02 = fmaf(u02, mm0, tv02);
    tv10 = fmaf(u10, mm1, tv10); tv11 = fmaf(u11, mm1, tv11); tv12 = fmaf(u12, mm1, tv12);
    if ((c & 7) == 7) __syncthreads();   // phase-lock waves for L1 reuse of rW2T stream
  }

  // mixing per atom
#pragma unroll
  for (int s = 0; s < 2; ++s){
    int a = w*2 + s;
    float m0 = mf[s][0], m1 = mf[s][1], m2 = mf[s][2];
    float muV0=0,muV1=0,muV2=0,muW0=0,muW1=0,muW2=0;
#pragma unroll
    for (int k = 0; k < 64; ++k){
      float b0 = mus[a][0][k], b1 = mus[a][1][k], b2 = mus[a][2][k];
      float wv = Wm[k*128 + f];
      float ww = Wm[k*128 + 64 + f];
      muV0 = fmaf(b0, wv, muV0); muV1 = fmaf(b1, wv, muV1); muV2 = fmaf(b2, wv, muV2);
      muW0 = fmaf(b0, ww, muW0); muW1 = fmaf(b1, ww, muW1); muW2 = fmaf(b2, ww, muW2);
    }
    float muVn = sqrtf(muV0*muV0 + muV1*muV1 + muV2*muV2 + EPSV);
    avs[w][f] = qv[s]; avs[w][64 + f] = muVn;

    float a2acc = mb1[f];
#pragma unroll
    for (int k = 0; k < 128; ++k) a2acc = fmaf(avs[w][k], mW1[k*64 + f], a2acc);
    h2s[w][f] = silu_f(a2acc);

    float y0 = mb2[f], y1 = mb2[64+f], y2 = mb2[128+f];
#pragma unroll
    for (int k = 0; k < 64; ++k){
      float h = h2s[w][k];
      y0 = fmaf(h, mW2[k*192 + f],       y0);
      y1 = fmaf(h, mW2[k*192 + 64 + f],  y1);
      y2 = fmaf(h, mW2[k*192 + 128 + f], y2);
    }
    float dot = muV0*muW0 + muV1*muW1 + muV2*muW2;
    int n = base + s;
    if (n < Ntot){
      q[(size_t)n*64 + f] = qv[s] + y0 + y2*dot;
      float* mun = mu + (size_t)n*384;
      float t0 = (s==0)?tv00:tv10, t1 = (s==0)?tv01:tv11, t2 = (s==0)?tv02:tv12;
      mun[0*128 + f] = fmaf(y1, muW0, m0); mun[0*128 + 64 + f] = t0;
      mun[1*128 + f] = fmaf(y1, muW1, m1); mun[1*128 + 64 + f] = t1;
      mun[2*128 + f] = fmaf(y1, muW2, m2); mun[2*128 + 64 + f] = t2;
    }
  }
}

extern "C" void kernel_launch(void* const* d_in, const int* in_sizes, int n_in,
                              void* d_out, int out_size, void* d_ws, size_t ws_size,
                              hipStream_t stream)
{
  const int*   Z      = (const int*)  d_in[0];
  const float* Rij    = (const float*)d_in[1];
  const int*   idx_i  = (const int*)  d_in[2];
  const int*   idx_j  = (const int*)  d_in[3];
  const float* embed  = (const float*)d_in[5];
  const float* fW     = (const float*)d_in[6];
  const float* fb     = (const float*)d_in[7];
  const float* ctxW1  = (const float*)d_in[8];
  const float* ctxb1  = (const float*)d_in[9];
  const float* ctxW2  = (const float*)d_in[10];
  const float* ctxb2  = (const float*)d_in[11];
  const float* compW1 = (const float*)d_in[12];
  const float* compb1 = (const float*)d_in[13];
  const float* compW2 = (const float*)d_in[14];
  const float* compb2 = (const float*)d_in[15];
  const float* recW1  = (const float*)d_in[16];
  const float* recb1  = (const float*)d_in[17];
  const float* recW2  = (const float*)d_in[18];
  const float* recb2  = (const float*)d_in[19];
  const float* mixW1  = (const float*)d_in[20];
  const float* mixb1  = (const float*)d_in[21];
  const float* mixW2  = (const float*)d_in[22];
  const float* mixb2  = (const float*)d_in[23];
  const float* muMixW = (const float*)d_in[24];

  const int N = in_sizes[0];
  const int P = in_sizes[1] / 3;

  float* ws    = (float*)d_ws;
  float* pair  = ws;                         // P*24
  float* q     = pair  + (size_t)P*24;       // N*64
  float* mu    = q     + (size_t)N*64;       // N*384
  float* X     = mu    + (size_t)N*384;      // N*192
  float* CV    = X     + (size_t)N*192;      // N*192
  float* dq    = CV    + (size_t)N*192;      // N*64
  float* dmu   = dq    + (size_t)N*64;       // N*192
  float* rW2T  = dmu   + (size_t)N*192;      // 2*64*32*64 = 262144
  float* rb2T  = rW2T  + (size_t)262144;     // 2*64*64   = 8192

  k_pairprep<<<(P + 255)/256, 256, 0, stream>>>(Rij, pair, P);
  k_transpose_w<<<(262144 + 255)/256, 256, 0, stream>>>(recW2, recb2, rW2T, rb2T);
  hipMemsetAsync(mu, 0, (size_t)N*384*sizeof(float), stream);
  k_init_q<<<(N*FD + 255)/256, 256, 0, stream>>>(Z, embed, q, N);

  const int ablk4 = (N + 3) / 4;
  const int ablk8 = (N + 7) / 8;
  const int pblk  = (P + 3) / 4;
  for (int l = 0; l < 2; ++l){
    hipMemsetAsync(dq,  0, (size_t)N*64 *sizeof(float), stream);
    hipMemsetAsync(dmu, 0, (size_t)N*192*sizeof(float), stream);
    k_atom_pre<<<ablk4, 256, 0, stream>>>(q, mu,
        ctxW1 + (size_t)l*64*64,  ctxb1 + (size_t)l*64,
        ctxW2 + (size_t)l*64*192, ctxb2 + (size_t)l*192,
        compW1 + (size_t)l*128*32, compb1 + (size_t)l*32,
        compW2 + (size_t)l*32*64,  compb2 + (size_t)l*64,
        X, CV, N);
    k_edge<<<pblk, 256, 0, stream>>>(pair, idx_i, idx_j, fW, fb, X, CV, dq, dmu, l, P);
    k_atom_post<<<ablk8, 256, 0, stream>>>(q, mu, dq, dmu, CV,
        recW1 + (size_t)l*64*32,  recb1 + (size_t)l*32,
        rW2T  + (size_t)l*131072, rb2T + (size_t)l*4096,
        mixW1 + (size_t)l*128*64, mixb1 + (size_t)l*64,
        mixW2 + (size_t)l*64*192, mixb2 + (size_t)l*192,
        muMixW + (size_t)l*64*128, N);
  }

  hipMemcpyAsync(d_out, q, (size_t)N*64*sizeof(float), hipMemcpyDeviceToDevice, stream);
  hipMemcpyAsync((float*)d_out + (size_t)N*64, mu, (size_t)N*384*sizeof(float),
                 hipMemcpyDeviceToDevice, stream);
}

// Round 3
// 1728.105 us; speedup vs baseline: 2.4969x; 2.4969x over previous
//
#include <hip/hip_runtime.h>
#include <math.h>

#define FD 64
#define NRBF 20
#define CUT 5.0f
#define EPSV 1e-8f
#define PI_F 3.14159265358979f

__device__ __forceinline__ float wredsum(float v){
#pragma unroll
  for (int m = 32; m >= 1; m >>= 1) v += __shfl_xor(v, m, 64);
  return v;
}
__device__ __forceinline__ float wredmax(float v){
#pragma unroll
  for (int m = 32; m >= 1; m >>= 1) v = fmaxf(v, __shfl_xor(v, m, 64));
  return v;
}
__device__ __forceinline__ float silu_f(float x){ return x * (1.0f / (1.0f + __expf(-x))); }

// ---- K0: per-pair precompute: dir(3), fcut(1), phi*fcut(20) -> 24 floats ----
__global__ __launch_bounds__(256) void k_pairprep(const float* __restrict__ Rij,
                                                  float* __restrict__ pair, int P)
{
  int p = blockIdx.x * blockDim.x + threadIdx.x;
  if (p >= P) return;
  float rx = Rij[3*p+0], ry = Rij[3*p+1], rz = Rij[3*p+2];
  float d = sqrtf(rx*rx + ry*ry + rz*rz);
  float inv = 1.0f / d;
  float fc = (d < CUT) ? 0.5f * (__cosf(PI_F * d / CUT) + 1.0f) : 0.0f;
  float* pr = pair + (size_t)p * 24;
  pr[0] = rx*inv; pr[1] = ry*inv; pr[2] = rz*inv; pr[3] = fc;
  const float width = CUT / (float)(NRBF - 1);
#pragma unroll
  for (int r = 0; r < NRBF; ++r){
    float t = (d - width * (float)r) / width;
    pr[4+r] = __expf(-0.5f * t * t) * fc;
  }
}

// ---- transpose+swizzle rec_W2 -> rW2S[l][c][f][kq^(f&7)][km], rb2 -> rb2T[l][c][f] ----
// element (l,c,k,f): stored at (((l*64+c)*64+f)*32 + ((k>>2)^(f&7))*4 + (k&3))
__global__ __launch_bounds__(256) void k_transpose_w(const float* __restrict__ rW2,
                                                     const float* __restrict__ rb2,
                                                     float* __restrict__ rW2S,
                                                     float* __restrict__ rb2T)
{
  int t = blockIdx.x * blockDim.x + threadIdx.x;
  if (t < 2*64*32*64){
    int km = t & 3;
    int kq = (t >> 2) & 7;
    int f  = (t >> 5) & 63;
    int c  = (t >> 11) & 63;
    int l  = t >> 17;
    int k  = ((kq ^ (f & 7)) << 2) | km;
    rW2S[t] = rW2[((size_t)(l*32 + k))*4096 + f*64 + c];
  }
  if (t < 2*64*64){
    int f = t & 63, c = (t >> 6) & 63, l = t >> 12;
    rb2T[t] = rb2[(size_t)l*4096 + f*64 + c];
  }
}

// ---- K_init: q = embed[Z] ----
__global__ __launch_bounds__(256) void k_init_q(const int* __restrict__ Z,
                                                const float* __restrict__ embed,
                                                float* __restrict__ q, int Ntot)
{
  int t = blockIdx.x * blockDim.x + threadIdx.x;
  if (t >= Ntot * FD) return;
  int n = t >> 6, f = t & 63;
  q[t] = embed[Z[n]*FD + f];
}

// ---- K1: per-atom: X = silu(q@cW1+cb1)@cW2+cb2 ; CV = compress(mu) ----
__global__ __launch_bounds__(256) void k_atom_pre(
    const float* __restrict__ q, const float* __restrict__ mu,
    const float* __restrict__ cW1, const float* __restrict__ cb1,
    const float* __restrict__ cW2, const float* __restrict__ cb2,
    const float* __restrict__ pW1, const float* __restrict__ pb1,
    const float* __restrict__ pW2, const float* __restrict__ pb2,
    float* __restrict__ X, float* __restrict__ CV, int Ntot)
{
  __shared__ float qs[4][64];
  __shared__ float h1[4][64];
  __shared__ float sbuf[4][128];
  __shared__ float hc[4][32];
  int w = threadIdx.x >> 6;
  int f = threadIdx.x & 63;
  int n = blockIdx.x * 4 + w;
  bool ok = (n < Ntot);
  if (!ok) n = Ntot - 1;

  float qv = q[(size_t)n*64 + f];
  qs[w][f] = qv;

  const float* mun = mu + (size_t)n * 384;
  float m0a = mun[0*128 + f],      m1a = mun[1*128 + f],      m2a = mun[2*128 + f];
  float m0b = mun[0*128 + 64 + f], m1b = mun[1*128 + 64 + f], m2b = mun[2*128 + 64 + f];
  sbuf[w][f]      = sqrtf(m0a*m0a + m1a*m1a + m2a*m2a + EPSV);
  sbuf[w][64 + f] = sqrtf(m0b*m0b + m1b*m1b + m2b*m2b + EPSV);

  float acc = cb1[f];
#pragma unroll
  for (int k = 0; k < 64; ++k) acc = fmaf(qs[w][k], cW1[k*64 + f], acc);
  h1[w][f] = silu_f(acc);

  float x0 = cb2[f], x1 = cb2[64+f], x2 = cb2[128+f];
#pragma unroll
  for (int k = 0; k < 64; ++k){
    float h = h1[w][k];
    x0 = fmaf(h, cW2[k*192 + f],       x0);
    x1 = fmaf(h, cW2[k*192 + 64 + f],  x1);
    x2 = fmaf(h, cW2[k*192 + 128 + f], x2);
  }
  if (ok){
    float* Xn = X + (size_t)n*192;
    Xn[f] = x0; Xn[64+f] = x1; Xn[128+f] = x2;
  }

  int ki = f & 31;
  float ah = pb1[ki];
#pragma unroll
  for (int c = 0; c < 128; ++c) ah = fmaf(sbuf[w][c], pW1[c*32 + ki], ah);
  if (f < 32) hc[w][f] = fmaxf(ah, 0.0f);

  float logit = pb2[f];
#pragma unroll
  for (int k = 0; k < 32; ++k) logit = fmaf(hc[w][k], pW2[k*64 + f], logit);
  float mx = wredmax(logit);
  float e  = __expf(logit - mx);
  float se = wredsum(e);
  float wt = e / se;
  float v0 = wredsum(m0a + m0b);
  float v1 = wredsum(m1a + m1b);
  float v2 = wredsum(m2a + m2b);
  if (ok){
    float* cvn = CV + (size_t)n*192;
    cvn[f] = v0 * wt; cvn[64+f] = v1 * wt; cvn[128+f] = v2 * wt;
  }
}

// ---- K2: per-pair: filters on the fly, gather X[j], CV[j], atomic scatter to i ----
__global__ __launch_bounds__(256) void k_edge(
    const float* __restrict__ pair, const int* __restrict__ idx_i, const int* __restrict__ idx_j,
    const float* __restrict__ fW, const float* __restrict__ fb,
    const float* __restrict__ X, const float* __restrict__ CV,
    float* __restrict__ dq, float* __restrict__ dmu, int l, int P)
{
  int w = threadIdx.x >> 6;
  int f = threadIdx.x & 63;
  int p = blockIdx.x * 4 + w;
  if (p >= P) return;
  const float* pr = pair + (size_t)p * 24;
  float d0 = pr[0], d1 = pr[1], d2 = pr[2], fc = pr[3];
  int i = idx_i[p], j = idx_j[p];
  const int col = l * 192;
  float w0 = fb[col + f] * fc, w1 = fb[col + 64 + f] * fc, w2 = fb[col + 128 + f] * fc;
#pragma unroll
  for (int r = 0; r < NRBF; ++r){
    float ph = pr[4 + r];
    const float* fr = fW + r*384 + col;
    w0 = fmaf(ph, fr[f],       w0);
    w1 = fmaf(ph, fr[64 + f],  w1);
    w2 = fmaf(ph, fr[128 + f], w2);
  }
  const float* Xj = X + (size_t)j * 192;
  float dqv = Xj[f]       * w0;
  float dmR = Xj[64 + f]  * w1;
  float dmm = Xj[128 + f] * w2;
  const float* cvj = CV + (size_t)j * 192;
  atomicAdd(&dq[(size_t)i*64 + f], dqv);
  atomicAdd(&dmu[(size_t)i*192 + f],       fmaf(dmR, d0, dmm * cvj[f]));
  atomicAdd(&dmu[(size_t)i*192 + 64 + f],  fmaf(dmR, d1, dmm * cvj[64 + f]));
  atomicAdd(&dmu[(size_t)i*192 + 128 + f], fmaf(dmR, d2, dmm * cvj[128 + f]));
}

// ---- K3a: tv only. 8 atoms/block (2 per wave). Weight tiles staged in LDS,
// bank-balanced via kq^(f&7) swizzle (pre-baked in rW2S). Writes MUI and TV. ----
__global__ __launch_bounds__(256) void k_tv(
    const float* __restrict__ dmuA, const float* __restrict__ CV,
    const float* __restrict__ rW1, const float* __restrict__ rb1,
    const float* __restrict__ rW2S, const float* __restrict__ rb2Tl,
    float* __restrict__ MUI, float* __restrict__ TV, int Ntot)
{
  __shared__ float mus[8][3][64];   // 6 KB
  __shared__ float svs[8][64];      // 2 KB
  __shared__ float4 wt4[4096];      // 64 KB: 8 c x 64 f x 8 float4
  __shared__ float rbt[8][64];      // 2 KB
  int t = threadIdx.x;
  int w = t >> 6, f = t & 63;
  int base = blockIdx.x * 8;

  // phase 1: mu_int for this block's 8 atoms (each wave handles 2)
#pragma unroll
  for (int s = 0; s < 2; ++s){
    int a = w*2 + s;
    int n = base + a; bool ok = (n < Ntot); if (!ok) n = Ntot - 1;
    const float* dmn = dmuA + (size_t)n*192;
    const float* cvn = CV   + (size_t)n*192;
    float m0 = dmn[f]       + cvn[f];
    float m1 = dmn[64 + f]  + cvn[64 + f];
    float m2 = dmn[128 + f] + cvn[128 + f];
    mus[a][0][f] = m0; mus[a][1][f] = m1; mus[a][2][f] = m2;
    svs[a][f] = sqrtf(m0*m0 + m1*m1 + m2*m2 + EPSV);
    if (ok){
      float* mo = MUI + (size_t)n*192;
      mo[f] = m0; mo[64+f] = m1; mo[128+f] = m2;
    }
  }
  __syncthreads();

  // phase 2: h for both atoms, lane-split (lanes 0-31 -> atom w*2, 32-63 -> w*2+1)
  int ki = f & 31;
  int a_h = w*2 + (f >> 5);
  float ah = rb1[ki];
#pragma unroll
  for (int c = 0; c < 64; ++c) ah = fmaf(svs[a_h][c], rW1[c*32 + ki], ah);
  ah = fmaxf(ah, 0.0f);
  float hreg[2][32];
#pragma unroll
  for (int k = 0; k < 32; ++k){
    hreg[0][k] = __shfl(ah, k, 64);
    hreg[1][k] = __shfl(ah, 32 + k, 64);
  }

  const int a0 = w*2, a1 = a0 + 1;
  float mf00 = mus[a0][0][f], mf01 = mus[a0][1][f], mf02 = mus[a0][2][f];
  float mf10 = mus[a1][0][f], mf11 = mus[a1][1][f], mf12 = mus[a1][2][f];
  float tv00=0,tv01=0,tv02=0, tv10=0,tv11=0,tv12=0;
  const int sw8 = (f & 7);

  for (int ct = 0; ct < 8; ++ct){
    __syncthreads();   // previous tile fully consumed
    const float4* src = (const float4*)rW2S + (size_t)ct*4096;
#pragma unroll
    for (int i = 0; i < 16; ++i) wt4[t + i*256] = src[t + i*256];
    if (t < 128) ((float4*)rbt)[t] = ((const float4*)(rb2Tl + ct*512))[t];
    __syncthreads();

#pragma unroll
    for (int cc = 0; cc < 8; ++cc){
      int c = ct*8 + cc;
      float u00 = mus[a0][0][c], u01 = mus[a0][1][c], u02 = mus[a0][2][c];
      float u10 = mus[a1][0][c], u11 = mus[a1][1][c], u12 = mus[a1][2][c];
      float g0 = u00*mf00 + u01*mf01 + u02*mf02;
      float g1 = u10*mf10 + u11*mf11 + u12*mf12;
      float acc0 = rbt[cc][f];
      float acc1 = acc0;
      const float4* wrow = &wt4[(cc*64 + f)*8];
#pragma unroll
      for (int kq = 0; kq < 8; ++kq){
        float4 wv = wrow[kq ^ sw8];
        int k0 = kq*4;
        acc0 = fmaf(hreg[0][k0+0], wv.x, acc0);
        acc0 = fmaf(hreg[0][k0+1], wv.y, acc0);
        acc0 = fmaf(hreg[0][k0+2], wv.z, acc0);
        acc0 = fmaf(hreg[0][k0+3], wv.w, acc0);
        acc1 = fmaf(hreg[1][k0+0], wv.x, acc1);
        acc1 = fmaf(hreg[1][k0+1], wv.y, acc1);
        acc1 = fmaf(hreg[1][k0+2], wv.z, acc1);
        acc1 = fmaf(hreg[1][k0+3], wv.w, acc1);
      }
      float mm0 = acc0 * g0, mm1 = acc1 * g1;
      tv00 = fmaf(u00, mm0, tv00); tv01 = fmaf(u01, mm0, tv01); tv02 = fmaf(u02, mm0, tv02);
      tv10 = fmaf(u10, mm1, tv10); tv11 = fmaf(u11, mm1, tv11); tv12 = fmaf(u12, mm1, tv12);
    }
  }

  int n0 = base + a0, n1 = base + a1;
  if (n0 < Ntot){
    float* tvp = TV + (size_t)n0*192;
    tvp[f] = tv00; tvp[64+f] = tv01; tvp[128+f] = tv02;
  }
  if (n1 < Ntot){
    float* tvp = TV + (size_t)n1*192;
    tvp[f] = tv10; tvp[64+f] = tv11; tvp[128+f] = tv12;
  }
}

// ---- K3b: mixing tail. 1 atom/wave, wave-private LDS, low registers. ----
__global__ __launch_bounds__(256) void k_mix(
    float* __restrict__ q, float* __restrict__ mu,
    const float* __restrict__ dq, const float* __restrict__ MUI, const float* __restrict__ TV,
    const float* __restrict__ mW1, const float* __restrict__ mb1,
    const float* __restrict__ mW2, const float* __restrict__ mb2,
    const float* __restrict__ Wm, int Ntot)
{
  __shared__ float mus[4][3][64];
  __shared__ float avs[4][128];
  __shared__ float h2s[4][64];
  int w = threadIdx.x >> 6;
  int f = threadIdx.x & 63;
  int n = blockIdx.x * 4 + w;
  bool ok = (n < Ntot);
  if (!ok) n = Ntot - 1;

  float qn = q[(size_t)n*64 + f] + dq[(size_t)n*64 + f];
  const float* mi = MUI + (size_t)n*192;
  float m0 = mi[f], m1 = mi[64 + f], m2 = mi[128 + f];
  mus[w][0][f] = m0; mus[w][1][f] = m1; mus[w][2][f] = m2;

  float muV0=0,muV1=0,muV2=0,muW0=0,muW1=0,muW2=0;
#pragma unroll
  for (int k = 0; k < 64; ++k){
    float b0 = mus[w][0][k], b1 = mus[w][1][k], b2 = mus[w][2][k];
    float wv = Wm[k*128 + f];
    float ww = Wm[k*128 + 64 + f];
    muV0 = fmaf(b0, wv, muV0); muV1 = fmaf(b1, wv, muV1); muV2 = fmaf(b2, wv, muV2);
    muW0 = fmaf(b0, ww, muW0); muW1 = fmaf(b1, ww, muW1); muW2 = fmaf(b2, ww, muW2);
  }
  float muVn = sqrtf(muV0*muV0 + muV1*muV1 + muV2*muV2 + EPSV);
  avs[w][f] = qn; avs[w][64 + f] = muVn;

  float a2acc = mb1[f];
#pragma unroll
  for (int k = 0; k < 128; ++k) a2acc = fmaf(avs[w][k], mW1[k*64 + f], a2acc);
  h2s[w][f] = silu_f(a2acc);

  float y0 = mb2[f], y1 = mb2[64+f], y2 = mb2[128+f];
#pragma unroll
  for (int k = 0; k < 64; ++k){
    float h = h2s[w][k];
    y0 = fmaf(h, mW2[k*192 + f],       y0);
    y1 = fmaf(h, mW2[k*192 + 64 + f],  y1);
    y2 = fmaf(h, mW2[k*192 + 128 + f], y2);
  }
  float dot = muV0*muW0 + muV1*muW1 + muV2*muW2;
  if (ok){
    q[(size_t)n*64 + f] = qn + y0 + y2*dot;
    const float* tvp = TV + (size_t)n*192;
    float* mun = mu + (size_t)n*384;
    mun[0*128 + f] = fmaf(y1, muW0, m0); mun[0*128 + 64 + f] = tvp[f];
    mun[1*128 + f] = fmaf(y1, muW1, m1); mun[1*128 + 64 + f] = tvp[64+f];
    mun[2*128 + f] = fmaf(y1, muW2, m2); mun[2*128 + 64 + f] = tvp[128+f];
  }
}

extern "C" void kernel_launch(void* const* d_in, const int* in_sizes, int n_in,
                              void* d_out, int out_size, void* d_ws, size_t ws_size,
                              hipStream_t stream)
{
  const int*   Z      = (const int*)  d_in[0];
  const float* Rij    = (const float*)d_in[1];
  const int*   idx_i  = (const int*)  d_in[2];
  const int*   idx_j  = (const int*)  d_in[3];
  const float* embed  = (const float*)d_in[5];
  const float* fW     = (const float*)d_in[6];
  const float* fb     = (const float*)d_in[7];
  const float* ctxW1  = (const float*)d_in[8];
  const float* ctxb1  = (const float*)d_in[9];
  const float* ctxW2  = (const float*)d_in[10];
  const float* ctxb2  = (const float*)d_in[11];
  const float* compW1 = (const float*)d_in[12];
  const float* compb1 = (const float*)d_in[13];
  const float* compW2 = (const float*)d_in[14];
  const float* compb2 = (const float*)d_in[15];
  const float* recW1  = (const float*)d_in[16];
  const float* recb1  = (const float*)d_in[17];
  const float* recW2  = (const float*)d_in[18];
  const float* recb2  = (const float*)d_in[19];
  const float* mixW1  = (const float*)d_in[20];
  const float* mixb1  = (const float*)d_in[21];
  const float* mixW2  = (const float*)d_in[22];
  const float* mixb2  = (const float*)d_in[23];
  const float* muMixW = (const float*)d_in[24];

  const int N = in_sizes[0];
  const int P = in_sizes[1] / 3;

  float* ws    = (float*)d_ws;
  float* pair  = ws;                         // P*24
  float* q     = pair  + (size_t)P*24;       // N*64
  float* mu    = q     + (size_t)N*64;       // N*384
  float* X     = mu    + (size_t)N*384;      // N*192  (reused as MUI after k_edge)
  float* CV    = X     + (size_t)N*192;      // N*192
  float* dq    = CV    + (size_t)N*192;      // N*64
  float* dmu   = dq    + (size_t)N*64;       // N*192
  float* rW2S  = dmu   + (size_t)N*192;      // 262144
  float* rb2T  = rW2S  + (size_t)262144;     // 8192
  float* TV    = rb2T  + (size_t)8192;       // N*192
  float* MUI   = X;                          // overlay: X dead after k_edge

  k_pairprep<<<(P + 255)/256, 256, 0, stream>>>(Rij, pair, P);
  k_transpose_w<<<(262144 + 255)/256, 256, 0, stream>>>(recW2, recb2, rW2S, rb2T);
  hipMemsetAsync(mu, 0, (size_t)N*384*sizeof(float), stream);
  k_init_q<<<(N*FD + 255)/256, 256, 0, stream>>>(Z, embed, q, N);

  const int ablk4 = (N + 3) / 4;
  const int ablk8 = (N + 7) / 8;
  const int pblk  = (P + 3) / 4;
  for (int l = 0; l < 2; ++l){
    hipMemsetAsync(dq,  0, (size_t)N*64 *sizeof(float), stream);
    hipMemsetAsync(dmu, 0, (size_t)N*192*sizeof(float), stream);
    k_atom_pre<<<ablk4, 256, 0, stream>>>(q, mu,
        ctxW1 + (size_t)l*64*64,  ctxb1 + (size_t)l*64,
        ctxW2 + (size_t)l*64*192, ctxb2 + (size_t)l*192,
        compW1 + (size_t)l*128*32, compb1 + (size_t)l*32,
        compW2 + (size_t)l*32*64,  compb2 + (size_t)l*64,
        X, CV, N);
    k_edge<<<pblk, 256, 0, stream>>>(pair, idx_i, idx_j, fW, fb, X, CV, dq, dmu, l, P);
    k_tv<<<ablk8, 256, 0, stream>>>(dmu, CV,
        recW1 + (size_t)l*64*32, recb1 + (size_t)l*32,
        rW2S + (size_t)l*131072, rb2T + (size_t)l*4096,
        MUI, TV, N);
    k_mix<<<ablk4, 256, 0, stream>>>(q, mu, dq, MUI, TV,
        mixW1 + (size_t)l*128*64, mixb1 + (size_t)l*64,
        mixW2 + (size_t)l*64*192, mixb2 + (size_t)l*192,
        muMixW + (size_t)l*64*128, N);
  }

  hipMemcpyAsync(d_out, q, (size_t)N*64*sizeof(float), hipMemcpyDeviceToDevice, stream);
  hipMemcpyAsync((float*)d_out + (size_t)N*64, mu, (size_t)N*384*sizeof(float),
                 hipMemcpyDeviceToDevice, stream);
}